// Round 15
// baseline (4494.612 us; speedup 1.0000x reference)
//
#include <hip/hip_runtime.h>

// ---------------- problem constants ----------------
static constexpr int B  = 4;
static constexpr int N0 = 2048;
static constexpr int LF = 8;
static constexpr int M1 = 1024, M2 = 512, M3 = 256;
static constexpr int O1 = 64, O2 = 128, O3 = 256;
static constexpr int NS1 = 12, NS2 = 8, NS3 = 4, NSQ = 4;
static constexpr int C1 = 67, C2 = 195, C3 = 387;
static constexpr int C41 = 68, C42 = 196, C43 = 388;  // padded to /4 (pad w=0, corr=0)
static constexpr long XS = 3 * (long)M1;  // xyz batch stride; L2/L3 = prefixes (r6)

// packed-weight pool offsets (floats): WP[c/4][o][4], zero-padded c
static constexpr int WP_E1 = 0;
static constexpr int WP_E2 = 4352;
static constexpr int WP_E3 = 29440;
static constexpr int WP_D1 = 128768;
static constexpr int WP_D2 = 133120;
static constexpr int WP_D3 = 158208;
static constexpr int WP_M1 = 257536;
static constexpr int WP_TOT = 286208;

__device__ __forceinline__ float sq3(float ax, float ay, float az,
                                     float bx, float by, float bz) {
  float dx = __fsub_rn(ax, bx), dy = __fsub_rn(ay, by), dz = __fsub_rn(az, bz);
  return __fadd_rn(__fadd_rn(__fmul_rn(dx, dx), __fmul_rn(dy, dy)),
                   __fmul_rn(dz, dz));
}

template <int CTRL>
__device__ __forceinline__ int dpp_i(int v) {
  return __builtin_amdgcn_update_dpp(v, v, CTRL, 0xf, 0xf, false);
}
// f32 max step (1 combine op; valid for values >= 0; self-fallback idempotent)
template <int CTRL>
__device__ __forceinline__ float dpp_maxf(float m) {
  const float o = __uint_as_float((unsigned)dpp_i<CTRL>((int)__float_as_uint(m)));
  return fmaxf(m, o);
}
// u32 min step
template <int CTRL>
__device__ __forceinline__ unsigned dpp_minu(unsigned v) {
  const unsigned o = (unsigned)dpp_i<CTRL>((int)v);
  return o < v ? o : v;
}
// u64 (hi,lo) min step — knn extraction
template <int CTRL>
__device__ __forceinline__ void dpp_min64_step(unsigned& hi, unsigned& lo) {
  const unsigned ohi = (unsigned)dpp_i<CTRL>((int)hi);
  const unsigned olo = (unsigned)dpp_i<CTRL>((int)lo);
  const bool take = (ohi < hi) || (ohi == hi && olo < lo);
  hi = take ? ohi : hi;
  lo = take ? olo : lo;
}

// elementwise 3-way weighted sum, numpy op order, per component (bit-exact)
__device__ __forceinline__ float4 wsum3(float4 a, float4 b, float4 c,
                                        float w0, float w1, float w2) {
  float4 r;
  r.x = __fadd_rn(__fadd_rn(__fmul_rn(a.x, w0), __fmul_rn(b.x, w1)), __fmul_rn(c.x, w2));
  r.y = __fadd_rn(__fadd_rn(__fmul_rn(a.y, w0), __fmul_rn(b.y, w1)), __fmul_rn(c.y, w2));
  r.z = __fadd_rn(__fadd_rn(__fmul_rn(a.z, w0), __fmul_rn(b.z, w1)), __fmul_rn(c.z, w2));
  r.w = __fadd_rn(__fadd_rn(__fmul_rn(a.w, w0), __fmul_rn(b.w, w1)), __fmul_rn(c.w, w2));
  return r;
}

// ---------------- weight pack: W[o][c] -> WP[c/4][o][4] (pool pre-zeroed) ----
__global__ __launch_bounds__(256) void pack_w(
    const float* __restrict__ e1, const float* __restrict__ e2,
    const float* __restrict__ e3, const float* __restrict__ d1,
    const float* __restrict__ d2, const float* __restrict__ d3,
    const float* __restrict__ m1, float* __restrict__ dst) {
  int t = blockIdx.x * 256 + threadIdx.x;
  const float* src; int C, O; long dof;
  if (t < 4288) { src = e1; C = C1; O = O1; dof = WP_E1; }
  else if (t < 29248) { src = e2; C = C2; O = O2; dof = WP_E2; t -= 4288; }
  else if (t < 128320) { src = e3; C = C3; O = O3; dof = WP_E3; t -= 29248; }
  else if (t < 132608) { src = d1; C = C1; O = O1; dof = WP_D1; t -= 128320; }
  else if (t < 157568) { src = d2; C = C2; O = O2; dof = WP_D2; t -= 132608; }
  else if (t < 256640) { src = d3; C = C3; O = O3; dof = WP_D3; t -= 157568; }
  else if (t < 285312) { src = m1; C = 448; O = 64; dof = WP_M1; t -= 256640; }
  else return;
  const int o = t / C, c = t - o * C;
  dst[dof + ((long)(c >> 2) * O + o) * 4 + (c & 3)] = src[t];
}

// ---------------- furthest point sampling v10: single-wave, barrier-free -----
// r13 decomposition of fps8's 1180 cyc/iter: k-loop ~190 + reduce ~90 +
// ~900 cyc cross-wave machinery (barrier + LDS round-trip + 4-wave skew),
// proven mechanism-insensitive (r3/5/7/8: barrier 605 <= spin 659 ~= owner
// 660 us). fps10: ONE wave (K=32, dist in registers, launch_bounds(64,1) =>
// ~512-VGPR budget) pays 4x k-loop (~640 cyc) but the cross-wave block
// vanishes — only the 12-step DPP reduce + one broadcast sp[] fetch remain.
// Winner = (max dist, min index): f32-max reduce (dm>=0 => float order ==
// bit order) then u32-min over j among dist-ties; per-lane strict '>' over
// ascending k keeps first occurrence => jnp.argmax bit-exact (r13-proven).
template <int N, int NPOINT>
__global__ __launch_bounds__(64, 1) void fps10(const float* __restrict__ pts,
                                               long s1, long s2,
                                               float* __restrict__ out,
                                               long o1, long o2,
                                               const float* __restrict__ cfsrc,
                                               float* __restrict__ cfdst,
                                               int copy_y) {
  if ((int)blockIdx.y == copy_y) {  // merged copyframe (float4)
    const int b = blockIdx.x;
    const float4* s4 = (const float4*)(cfsrc + ((long)b * LF + (LF / 2 - 1)) * N0 * 3);
    float4* d4 = (float4*)(cfdst + (long)b * N0 * 3);
    for (int e = threadIdx.x; e < N0 * 3 / 4; e += 64) d4[e] = s4[e];
    return;
  }
  constexpr int K = N / 64;
  const float* p = pts + (long)blockIdx.x * s1 + (long)blockIdx.y * s2;
  float* outb = out + (long)blockIdx.x * o1 + (long)blockIdx.y * o2;
  const int lane = threadIdx.x;
  __shared__ float4 sp[N];
  __shared__ float sel[NPOINT * 3];
  float ppx[K], ppy[K], ppz[K], dist[K];
#pragma unroll
  for (int k = 0; k < K; ++k) {
    const int j = k * 64 + lane;
    const float x = p[3 * j + 0], y = p[3 * j + 1], z = p[3 * j + 2];
    ppx[k] = x; ppy[k] = y; ppz[k] = z;
    sp[j] = make_float4(x, y, z, 0.f);
    dist[k] = 1e10f;
  }
  // same-wave LDS RAW is in-order; no barrier needed anywhere in this kernel
  const float4 c0 = sp[0];
  float lx = c0.x, ly = c0.y, lz = c0.z;  // first selected = index 0
  for (int i = 0; i < NPOINT; ++i) {
    if (lane == 0) {
      sel[3 * i + 0] = lx; sel[3 * i + 1] = ly; sel[3 * i + 2] = lz;
    }
    float bdm = 0.f;
    int bj = 0;
#pragma unroll
    for (int k = 0; k < K; ++k) {
      const float d = sq3(ppx[k], ppy[k], ppz[k], lx, ly, lz);
      const float dm = fminf(dist[k], d);
      dist[k] = dm;
      const bool take = dm > bdm;  // strict > keeps smallest k (first occurrence)
      bdm = take ? dm : bdm;
      bj = take ? (k * 64 + lane) : bj;
    }
    float mx = bdm;
    mx = dpp_maxf<0x111>(mx);
    mx = dpp_maxf<0x112>(mx);
    mx = dpp_maxf<0x114>(mx);
    mx = dpp_maxf<0x118>(mx);
    mx = dpp_maxf<0x142>(mx);
    mx = dpp_maxf<0x143>(mx);
    const float wmax = __uint_as_float(
        (unsigned)__builtin_amdgcn_readlane((int)__float_as_uint(mx), 63));
    unsigned cand = (bdm == wmax) ? (unsigned)bj : 0xFFFFFFFFu;
    cand = dpp_minu<0x111>(cand);
    cand = dpp_minu<0x112>(cand);
    cand = dpp_minu<0x114>(cand);
    cand = dpp_minu<0x118>(cand);
    cand = dpp_minu<0x142>(cand);
    cand = dpp_minu<0x143>(cand);
    const int minj = __builtin_amdgcn_readlane((int)cand, 63);
    const float4 c = sp[minj];  // broadcast ds_read_b128
    lx = c.x; ly = c.y; lz = c.z;
  }
  for (int e = lane; e < NPOINT * 3; e += 64) outb[e] = sel[e];
}

// ---------------- wave-parallel ball query (first ns in-range, ascending) ----
template <int NS>
__device__ __forceinline__ void wave_bq(float qx, float qy, float qz,
                                        const float* __restrict__ src, int Ns,
                                        float r2, int* __restrict__ sidx, int lane) {
  int cnt = 0;
  for (int base = 0; base < Ns && cnt < NS; base += 64) {
    const int j = base + lane;
    bool in = false;
    if (j < Ns)
      in = sq3(qx, qy, qz, src[3 * j], src[3 * j + 1], src[3 * j + 2]) < r2;
    const unsigned long long mask = __ballot(in);
    const int pos = cnt + (int)__popcll(mask & ((1ull << lane) - 1ull));
    if (in && pos < NS) sidx[pos] = j;
    cnt += (int)__popcll(mask);
  }
  const int cc = cnt < NS ? cnt : NS;
  const int fill = (cc > 0) ? sidx[0] : 0;
  if (lane >= cc && lane < NS) sidx[lane] = fill;
}

// ---------------- fused multi-cell (+knn) dispatch (r13, measured floor) -----
struct FusedArgs {
  int n1, n2, n3, nk;
  const float *c1_xc, *c1_xp, *c1_W, *c1_Sp; float* c1_Sc;
  const float *c2_xc, *c2_xp, *c2_W, *c2_Sp, *c2_S1; float* c2_Sc;
  const float *c3_xc, *c3_xp, *c3_W, *c3_Sp, *c3_S2; float* c3_Sc;
  const float *k_xc, *k_frame;
  int *ii2, *ii1, *ii0;
  float *iw2, *iw1, *iw0;
  float r2c1, r2c2, r2q2, r2c3, r2q3;
};

__global__ __launch_bounds__(256) void fused_cells(FusedArgs a) {
  __shared__ __align__(16) float smem[3312];
  const int tid = threadIdx.x;
  const int lane = tid & 63;
  const int wave = tid >> 6;
  int bid = blockIdx.x;

  if (bid < a.n1) {  // -------- cell level-1 (4 wave-units/block) --------
    float* corr2 = smem + (size_t)wave * 828;  // [NS1][C41]=816 + 12 sidx
    int* sidx = (int*)(corr2 + 816);
    const int u = bid * 4 + wave;
    const int b = u >> 10, m = u & (M1 - 1);
    const float* p1 = a.c1_xc + (long)b * XS + 3 * m;
    const float p1x = p1[0], p1y = p1[1], p1z = p1[2];
    const float* p2b = a.c1_xp + (long)b * XS;
    wave_bq<NS1>(p1x, p1y, p1z, p2b, M1, a.r2c1, sidx, lane);
    __builtin_amdgcn_wave_barrier();
    for (int e = lane; e < NS1 * C41; e += 64) {
      const int s = e / C41, c = e - s * C41;
      const int j = sidx[s];
      float v;
      if (c < O1) {
        v = a.c1_Sp[((long)b * M1 + j) * O1 + c];
      } else if (c < C1) {
        const int d = c - O1;
        v = __fsub_rn(p2b[3 * j + d], (d == 0) ? p1x : ((d == 1) ? p1y : p1z));
      } else {
        v = 0.f;  // pad
      }
      corr2[e] = v;
    }
    __builtin_amdgcn_wave_barrier();
    const float4* wp4 = (const float4*)a.c1_W;
    float accs[NS1];
#pragma unroll
    for (int s = 0; s < NS1; ++s) accs[s] = 0.f;
    for (int q = 0; q < C41 / 4; ++q) {
      const float4 wv = wp4[(long)q * O1 + lane];
#pragma unroll
      for (int s = 0; s < NS1; ++s) {
        const float4 cv = *(const float4*)(corr2 + s * C41 + 4 * q);
        float acc = accs[s];
        acc = fmaf(wv.x, cv.x, acc);
        acc = fmaf(wv.y, cv.y, acc);
        acc = fmaf(wv.z, cv.z, acc);
        acc = fmaf(wv.w, cv.w, acc);
        accs[s] = acc;
      }
    }
    float best = accs[0];
#pragma unroll
    for (int s = 1; s < NS1; ++s) best = fmaxf(best, accs[s]);
    a.c1_Sc[((long)b * M1 + m) * O1 + lane] = best;
    return;
  }
  bid -= a.n1;

  if (bid < a.n2) {  // -------- cell level-2 (2 128-thr units/block) --------
    const int half = tid >> 7;
    const int ht = tid & 127;
    const int hw = (tid >> 6) & 1;
    float* base = smem + (size_t)half * 1644;
    float* corr2 = base;                 // [NS2][C42] = 1568
    int* sidx = (int*)(base + 1568);     // 8
    int* sfidx = (int*)(base + 1576);    // 4
    float* feat = base + 1580;           // 64
    const int u = bid * 2 + half;
    const int b = u >> 9, m = u & (M2 - 1);
    const float* p1 = a.c2_xc + (long)b * XS + 3 * m;
    const float p1x = p1[0], p1y = p1[1], p1z = p1[2];
    const float* p2b = a.c2_xp + (long)b * XS;
    if (hw == 0)
      wave_bq<NS2>(p1x, p1y, p1z, p2b, M2, a.r2c2, sidx, lane);
    else
      wave_bq<NSQ>(p1x, p1y, p1z, a.c2_xc + (long)b * XS, M1, a.r2q2, sfidx, lane);
    __syncthreads();
    if (ht < O1) {
      float bv = -3.0e38f;
#pragma unroll
      for (int s = 0; s < NSQ; ++s)
        bv = fmaxf(bv, a.c2_S1[((long)b * M1 + sfidx[s]) * O1 + ht]);
      feat[ht] = bv;
    }
    __syncthreads();
    for (int e = ht; e < NS2 * C42; e += 128) {
      const int s = e / C42, c = e - s * C42;
      const int j = sidx[s];
      float v;
      if (c < O2) {
        v = a.c2_Sp[((long)b * M2 + j) * O2 + c];
      } else if (c < O2 + O1) {
        v = feat[c - O2];
      } else if (c < C2) {
        const int d = c - O2 - O1;
        v = __fsub_rn(p2b[3 * j + d], (d == 0) ? p1x : ((d == 1) ? p1y : p1z));
      } else {
        v = 0.f;
      }
      corr2[e] = v;
    }
    __syncthreads();
    const float4* wp4 = (const float4*)a.c2_W;
    float accs[NS2];
#pragma unroll
    for (int s = 0; s < NS2; ++s) accs[s] = 0.f;
    for (int q = 0; q < C42 / 4; ++q) {
      const float4 wv = wp4[(long)q * O2 + ht];
#pragma unroll
      for (int s = 0; s < NS2; ++s) {
        const float4 cv = *(const float4*)(corr2 + s * C42 + 4 * q);
        float acc = accs[s];
        acc = fmaf(wv.x, cv.x, acc);
        acc = fmaf(wv.y, cv.y, acc);
        acc = fmaf(wv.z, cv.z, acc);
        acc = fmaf(wv.w, cv.w, acc);
        accs[s] = acc;
      }
    }
    float best = accs[0];
#pragma unroll
    for (int s = 1; s < NS2; ++s) best = fmaxf(best, accs[s]);
    a.c2_Sc[((long)b * M2 + m) * O2 + ht] = best;
    return;
  }
  bid -= a.n2;

  if (bid < a.n3) {  // -------- cell level-3 (1 unit/block, 256 thr) --------
    float* corr2 = smem;                 // [NS3][C43] = 1552
    int* sidx = (int*)(smem + 1552);
    int* sfidx = (int*)(smem + 1556);
    float* feat = smem + 1560;           // 128
    const int b = bid >> 8, m = bid & (M3 - 1);
    const float* p1 = a.c3_xc + (long)b * XS + 3 * m;
    const float p1x = p1[0], p1y = p1[1], p1z = p1[2];
    const float* p2b = a.c3_xp + (long)b * XS;
    if (wave == 0)
      wave_bq<NS3>(p1x, p1y, p1z, p2b, M3, a.r2c3, sidx, lane);
    else if (wave == 1)
      wave_bq<NSQ>(p1x, p1y, p1z, a.c3_xc + (long)b * XS, M2, a.r2q3, sfidx, lane);
    __syncthreads();
    if (tid < O2) {
      float bv = -3.0e38f;
#pragma unroll
      for (int s = 0; s < NSQ; ++s)
        bv = fmaxf(bv, a.c3_S2[((long)b * M2 + sfidx[s]) * O2 + tid]);
      feat[tid] = bv;
    }
    __syncthreads();
    for (int e = tid; e < NS3 * C43; e += 256) {
      const int s = e / C43, c = e - s * C43;
      const int j = sidx[s];
      float v;
      if (c < O3) {
        v = a.c3_Sp[((long)b * M3 + j) * O3 + c];
      } else if (c < O3 + O2) {
        v = feat[c - O3];
      } else if (c < C3) {
        const int d = c - O3 - O2;
        v = __fsub_rn(p2b[3 * j + d], (d == 0) ? p1x : ((d == 1) ? p1y : p1z));
      } else {
        v = 0.f;
      }
      corr2[e] = v;
    }
    __syncthreads();
    const float4* wp4 = (const float4*)a.c3_W;
    float accs[NS3];
#pragma unroll
    for (int s = 0; s < NS3; ++s) accs[s] = 0.f;
    for (int q = 0; q < C43 / 4; ++q) {
      const float4 wv = wp4[(long)q * O3 + tid];
#pragma unroll
      for (int s = 0; s < NS3; ++s) {
        const float4 cv = *(const float4*)(corr2 + s * C43 + 4 * q);
        float acc = accs[s];
        acc = fmaf(wv.x, cv.x, acc);
        acc = fmaf(wv.y, cv.y, acc);
        acc = fmaf(wv.z, cv.z, acc);
        acc = fmaf(wv.w, cv.w, acc);
        accs[s] = acc;
      }
    }
    float best = accs[0];
#pragma unroll
    for (int s = 1; s < NS3; ++s) best = fmaxf(best, accs[s]);
    a.c3_Sc[((long)b * M3 + m) * O3 + tid] = best;
    return;
  }
  bid -= a.n3;

  {  // -------- knn: wave-per-query 3-NN (3584 blocks: 512 + 1024 + 2048) -----
    int q, Mu, Mk;
    const float* unk; long ustr; int* oi; float* ow;
    if (bid < 512) {
      q = bid * 4 + wave; Mu = M2; Mk = M3; unk = a.k_xc; ustr = XS;
      oi = a.ii2; ow = a.iw2;
    } else if (bid < 1536) {
      q = (bid - 512) * 4 + wave; Mu = M1; Mk = M2; unk = a.k_xc; ustr = XS;
      oi = a.ii1; ow = a.iw1;
    } else {
      q = (bid - 1536) * 4 + wave; Mu = N0; Mk = M1; unk = a.k_frame; ustr = 3L * N0;
      oi = a.ii0; ow = a.iw0;
    }
    const int b = q / Mu, m = q - b * Mu;
    const float* qq = unk + (long)b * ustr + (long)m * 3;
    const float qx = qq[0], qy = qq[1], qz = qq[2];
    const float* s = a.k_xc + (long)b * XS;
    unsigned long long k0 = ~0ull, k1 = ~0ull, k2 = ~0ull;
    const int steps = Mk >> 6;
    for (int t7 = 0; t7 < steps; ++t7) {
      const int j = (t7 << 6) + lane;
      const float dd = sq3(qx, qy, qz, s[3 * j], s[3 * j + 1], s[3 * j + 2]);
      const unsigned long long key =
          ((unsigned long long)__float_as_uint(dd) << 32) | (unsigned)j;
      if (key < k0) { k2 = k1; k1 = k0; k0 = key; }
      else if (key < k1) { k2 = k1; k1 = key; }
      else if (key < k2) { k2 = key; }
    }
    float dw[3]; int jw[3];
#pragma unroll
    for (int r = 0; r < 3; ++r) {
      unsigned mhi = (unsigned)(k0 >> 32), mlo = (unsigned)k0;
      dpp_min64_step<0x111>(mhi, mlo);
      dpp_min64_step<0x112>(mhi, mlo);
      dpp_min64_step<0x114>(mhi, mlo);
      dpp_min64_step<0x118>(mhi, mlo);
      dpp_min64_step<0x142>(mhi, mlo);
      dpp_min64_step<0x143>(mhi, mlo);
      const unsigned whi = (unsigned)__builtin_amdgcn_readlane((int)mhi, 63);
      const unsigned wlo = (unsigned)__builtin_amdgcn_readlane((int)mlo, 63);
      const unsigned long long w = ((unsigned long long)whi << 32) | wlo;
      dw[r] = __uint_as_float(whi);
      jw[r] = (int)wlo;
      if (k0 == w) { k0 = k1; k1 = k2; k2 = ~0ull; }
    }
    const float r0 = 1.0f / __fadd_rn(dw[0], 1e-8f);
    const float r1 = 1.0f / __fadd_rn(dw[1], 1e-8f);
    const float r2 = 1.0f / __fadd_rn(dw[2], 1e-8f);
    const float sum = __fadd_rn(__fadd_rn(r0, r1), r2);
    if (lane == 0) {
      ow[q * 3 + 0] = r0 / sum;
      ow[q * 3 + 1] = r1 / sum;
      ow[q * 3 + 2] = r2 / sum;
      oi[q * 3 + 0] = jw[0];
      oi[q * 3 + 1] = jw[1];
      oi[q * 3 + 2] = jw[2];
    }
  }
}

// ---------------- buildl2 (float4 per thread, fully coalesced) ----------------
__global__ __launch_bounds__(256) void buildl2_kernel(const float* __restrict__ S3c,
                                                      const float* __restrict__ S2c,
                                                      const float* __restrict__ S1c,
                                                      const int* __restrict__ ii1,
                                                      const float* __restrict__ iw1,
                                                      const int* __restrict__ ii2,
                                                      const float* __restrict__ iw2,
                                                      float* __restrict__ l2) {
  const int t = blockIdx.x * 256 + threadIdx.x;  // exact: B*M1*112
  const int bm = t / 112;
  const int c0 = (t - bm * 112) * 4;
  const int b = bm >> 10;
  const int* id1 = ii1 + (long)bm * 3;
  const float* w1 = iw1 + (long)bm * 3;
  float4 v;
  if (c0 < O3) {
    float4 v2[3];
#pragma unroll
    for (int k = 0; k < 3; ++k) {
      const int m2 = id1[k];
      const int* id2 = ii2 + ((long)b * M2 + m2) * 3;
      const float* w2 = iw2 + ((long)b * M2 + m2) * 3;
      const float4 s0 = *(const float4*)(S3c + ((long)b * M3 + id2[0]) * O3 + c0);
      const float4 s1 = *(const float4*)(S3c + ((long)b * M3 + id2[1]) * O3 + c0);
      const float4 s2 = *(const float4*)(S3c + ((long)b * M3 + id2[2]) * O3 + c0);
      v2[k] = wsum3(s0, s1, s2, w2[0], w2[1], w2[2]);
    }
    v = wsum3(v2[0], v2[1], v2[2], w1[0], w1[1], w1[2]);
  } else if (c0 < 384) {
    const int cc = c0 - O3;
    const float4 s0 = *(const float4*)(S2c + ((long)b * M2 + id1[0]) * O2 + cc);
    const float4 s1 = *(const float4*)(S2c + ((long)b * M2 + id1[1]) * O2 + cc);
    const float4 s2 = *(const float4*)(S2c + ((long)b * M2 + id1[2]) * O2 + cc);
    v = wsum3(s0, s1, s2, w1[0], w1[1], w1[2]);
  } else {
    v = *(const float4*)(S1c + (long)bm * O1 + (c0 - 384));
  }
  *(float4*)(l2 + (long)bm * 448 + c0) = v;
}

// ---------------- mlp: interp-to-l1 + 2-layer MLP + frame update -------------
__global__ __launch_bounds__(256) void mlp_kernel(const float* __restrict__ l2,
                                                  const int* __restrict__ ii,
                                                  const float* __restrict__ iw,
                                                  const float* __restrict__ W1P,
                                                  const float* __restrict__ b1,
                                                  const float* __restrict__ W2,
                                                  const float* __restrict__ b2,
                                                  float* __restrict__ frame,
                                                  float* __restrict__ out, int td) {
  __shared__ __align__(16) float smem[4 * 512];
  const int lane = threadIdx.x & 63;
  const int wave = threadIdx.x >> 6;
  float* col = smem + (size_t)wave * 512;
  float* h = col + 448;
  const int u = blockIdx.x * 4 + wave;  // exact: B*N0 units
  const int b = u >> 11, n = u & (N0 - 1);
  const int* id = ii + (long)u * 3;
  const float* w = iw + (long)u * 3;
  const float w0 = w[0], w1 = w[1], w2v = w[2];
  const float4* r0 = (const float4*)(l2 + ((long)b * M1 + id[0]) * 448);
  const float4* r1 = (const float4*)(l2 + ((long)b * M1 + id[1]) * 448);
  const float4* r2 = (const float4*)(l2 + ((long)b * M1 + id[2]) * 448);
  float4* col4 = (float4*)col;
  for (int q = lane; q < 112; q += 64)
    col4[q] = wsum3(r0[q], r1[q], r2[q], w0, w1, w2v);
  __builtin_amdgcn_wave_barrier();
  const float4* wp4 = (const float4*)W1P;
  float acc = b1[lane];
  for (int q = 0; q < 112; ++q) {
    const float4 wv = wp4[(long)q * 64 + lane];
    const float4 cv = col4[q];
    acc = fmaf(wv.x, cv.x, acc);
    acc = fmaf(wv.y, cv.y, acc);
    acc = fmaf(wv.z, cv.z, acc);
    acc = fmaf(wv.w, cv.w, acc);
  }
  h[lane] = fmaxf(acc, 0.0f);
  __builtin_amdgcn_wave_barrier();
  if (lane < 3) {
    const float* w2r = W2 + lane * 64;
    float acc2 = b2[lane];
    for (int c = 0; c < 64; ++c) acc2 = fmaf(w2r[c], h[c], acc2);
    const float nf = frame[(long)u * 3 + lane] + acc2;
    frame[(long)u * 3 + lane] = nf;
    out[(((long)b * 4 + td) * N0 + n) * 3 + lane] = nf;
  }
}

extern "C" void kernel_launch(void* const* d_in, const int* in_sizes, int n_in,
                              void* d_out, int out_size, void* d_ws, size_t ws_size,
                              hipStream_t stream) {
  const float* xyzs = (const float*)d_in[0];
  const float* enw[3] = {(const float*)d_in[1], (const float*)d_in[2], (const float*)d_in[3]};
  const float* dew[3] = {(const float*)d_in[4], (const float*)d_in[5], (const float*)d_in[6]};
  const float* mw1 = (const float*)d_in[7];
  const float* mb1 = (const float*)d_in[8];
  const float* mw2 = (const float*)d_in[9];
  const float* mb2 = (const float*)d_in[10];
  float* out = (float*)d_out;

  float* ws = (float*)d_ws;
  size_t off = 0;
  auto alloc = [&](size_t nn) { float* p = ws + off; off += nn; return p; };
  const long st1 = (long)B * M1 * 3;
  float* frame = alloc((size_t)B * N0 * 3);
  float* xyz1e = alloc((size_t)4 * st1);
  float* xyz1d[2] = {alloc((size_t)st1), alloc((size_t)st1)};
  float* z1 = alloc((size_t)st1);
  float* S1bf[2] = {alloc((size_t)B * O1 * M1), alloc((size_t)B * O1 * M1)};
  float* S2bf[2] = {alloc((size_t)B * O2 * M2), alloc((size_t)B * O2 * M2)};
  float* S3bf[2] = {alloc((size_t)B * O3 * M3), alloc((size_t)B * O3 * M3)};
  float* l2 = alloc((size_t)B * 448 * M1);
  float* iw0 = alloc((size_t)B * N0 * 3);
  int* ii0 = (int*)alloc((size_t)B * N0 * 3);
  float* iw1 = alloc((size_t)B * M1 * 3);
  int* ii1 = (int*)alloc((size_t)B * M1 * 3);
  float* iw2 = alloc((size_t)B * M2 * 3);
  int* ii2 = (int*)alloc((size_t)B * M2 * 3);
  float* wt = alloc((size_t)WP_TOT);

  hipMemsetAsync(z1, 0, (size_t)st1 * 4, stream);
  hipMemsetAsync(S1bf[1], 0, (size_t)B * O1 * M1 * 4, stream);
  hipMemsetAsync(S2bf[1], 0, (size_t)B * O2 * M2 * 4, stream);
  hipMemsetAsync(S3bf[1], 0, (size_t)B * O3 * M3 * 4, stream);
  hipMemsetAsync(wt, 0, (size_t)WP_TOT * 4, stream);  // pad weights must be 0

  double r;
  r = 4.0 + 1e-6;             const float r2c1 = (float)(r * r);
  r = 2.0 * 4.0 / 4.0 + 1e-6; const float r2q2 = (float)(r * r);
  r = 2.0 * 4.0 + 1e-6;       const float r2c2 = (float)(r * r);
  r = 4.0 * 4.0 / 4.0 + 1e-6; const float r2q3 = (float)(r * r);
  r = 3.0 * 4.0 + 1e-6;       const float r2c3 = (float)(r * r);

  pack_w<<<dim3((285312 + 255) / 256), 256, 0, stream>>>(
      enw[0], enw[1], enw[2], dew[0], dew[1], dew[2], mw1, wt);

  // encoder FPS (4 timesteps) + merged copyframe (y==4), 64-thread blocks
  fps10<2048, 1024><<<dim3(B, 5), 64, 0, stream>>>(xyzs, (long)LF * N0 * 3,
                                                   (long)N0 * 3, xyz1e, XS, st1,
                                                   xyzs, frame, 4);

  // t=4: frame == xyzs[:,3] bit-exactly => reuse encoder t=3's FPS result.
  const float* x1_of_t[LF] = {
      xyz1e + 0 * st1, xyz1e + 1 * st1, xyz1e + 2 * st1, xyz1e + 3 * st1,
      xyz1e + 3 * st1, xyz1d[0], xyz1d[1], xyz1d[0]};

  const float* wp1[2] = {wt + WP_E1, wt + WP_D1};
  const float* wp2[2] = {wt + WP_E2, wt + WP_D2};
  const float* wp3[2] = {wt + WP_E3, wt + WP_D3};

  auto launch_fused = [&](int t1, int t2, int t3, int tk) {
    FusedArgs a{};
    int nb = 0;
    if (t1 >= 0) {
      a.n1 = B * M1 / 4;
      a.c1_xc = x1_of_t[t1];
      a.c1_xp = (t1 == 0) ? z1 : x1_of_t[t1 - 1];
      a.c1_W = wp1[t1 >= 4];
      a.c1_Sp = S1bf[1 - (t1 & 1)];
      a.c1_Sc = S1bf[t1 & 1];
      nb += a.n1;
    }
    if (t2 >= 0) {
      a.n2 = B * M2 / 2;
      a.c2_xc = x1_of_t[t2];
      a.c2_xp = (t2 == 0) ? z1 : x1_of_t[t2 - 1];
      a.c2_W = wp2[t2 >= 4];
      a.c2_Sp = S2bf[1 - (t2 & 1)];
      a.c2_S1 = S1bf[t2 & 1];
      a.c2_Sc = S2bf[t2 & 1];
      nb += a.n2;
    }
    if (t3 >= 0) {
      a.n3 = B * M3;
      a.c3_xc = x1_of_t[t3];
      a.c3_xp = (t3 == 0) ? z1 : x1_of_t[t3 - 1];
      a.c3_W = wp3[t3 >= 4];
      a.c3_Sp = S3bf[1 - (t3 & 1)];
      a.c3_S2 = S2bf[t3 & 1];
      a.c3_Sc = S3bf[t3 & 1];
      nb += a.n3;
    }
    if (tk >= 0) {
      a.nk = 3584;  // wave-per-query knn: 512 (ii2) + 1024 (ii1) + 2048 (ii0)
      a.k_xc = x1_of_t[tk];
      a.k_frame = frame;
      a.ii2 = ii2; a.ii1 = ii1; a.ii0 = ii0;
      a.iw2 = iw2; a.iw1 = iw1; a.iw0 = iw0;
      nb += a.nk;
    }
    a.r2c1 = r2c1; a.r2c2 = r2c2; a.r2q2 = r2q2; a.r2c3 = r2c3; a.r2q3 = r2q3;
    fused_cells<<<dim3((unsigned)nb), 256, 0, stream>>>(a);
  };

  auto tail = [&](int t) {
    buildl2_kernel<<<dim3(B * M1 * 112 / 256), 256, 0, stream>>>(
        S3bf[t & 1], S2bf[t & 1], S1bf[t & 1], ii1, iw1, ii2, iw2, l2);
    mlp_kernel<<<dim3(B * N0 / 4), 256, 0, stream>>>(
        l2, ii0, iw0, wt + WP_M1, mb1, mw2, mb2, frame, out, t - 4);
  };

  // encoder software pipeline + t=4 head (diagonal: independent tasks merged)
  launch_fused(0, -1, -1, -1);
  launch_fused(1, 0, -1, -1);
  launch_fused(2, 1, 0, -1);
  launch_fused(3, 2, 1, -1);
  launch_fused(4, 3, 2, 4);
  launch_fused(-1, 4, 3, -1);
  launch_fused(-1, -1, 4, -1);
  tail(4);

  for (int t = 5; t < LF; ++t) {
    fps10<2048, 1024><<<dim3(B, 1), 64, 0, stream>>>(frame, (long)N0 * 3, 0,
                                                     (float*)x1_of_t[t], XS, 0,
                                                     nullptr, nullptr, -1);
    launch_fused(t, -1, -1, t);
    launch_fused(-1, t, -1, -1);
    launch_fused(-1, -1, t, -1);
    tail(t);
  }
  (void)in_sizes; (void)n_in; (void)out_size; (void)ws_size;
}

// Round 16
// 2781.985 us; speedup vs baseline: 1.6156x; 1.6156x over previous
//
#include <hip/hip_runtime.h>

// ---------------- problem constants ----------------
static constexpr int B  = 4;
static constexpr int N0 = 2048;
static constexpr int LF = 8;
static constexpr int M1 = 1024, M2 = 512, M3 = 256;
static constexpr int O1 = 64, O2 = 128, O3 = 256;
static constexpr int NS1 = 12, NS2 = 8, NS3 = 4, NSQ = 4;
static constexpr int C1 = 67, C2 = 195, C3 = 387;
static constexpr int C41 = 68, C42 = 196, C43 = 388;  // padded to /4 (pad w=0, corr=0)
static constexpr long XS = 3 * (long)M1;  // xyz batch stride; L2/L3 = prefixes (r6)

// packed-weight pool offsets (floats): WP[c/4][o][4], zero-padded c
static constexpr int WP_E1 = 0;
static constexpr int WP_E2 = 4352;
static constexpr int WP_E3 = 29440;
static constexpr int WP_D1 = 128768;
static constexpr int WP_D2 = 133120;
static constexpr int WP_D3 = 158208;
static constexpr int WP_M1 = 257536;
static constexpr int WP_TOT = 286208;

__device__ __forceinline__ float sq3(float ax, float ay, float az,
                                     float bx, float by, float bz) {
  float dx = __fsub_rn(ax, bx), dy = __fsub_rn(ay, by), dz = __fsub_rn(az, bz);
  return __fadd_rn(__fadd_rn(__fmul_rn(dx, dx), __fmul_rn(dy, dy)),
                   __fmul_rn(dz, dz));
}

template <int CTRL>
__device__ __forceinline__ int dpp_i(int v) {
  return __builtin_amdgcn_update_dpp(v, v, CTRL, 0xf, 0xf, false);
}
// f32 max step (1 combine op; valid for values >= 0; self-fallback idempotent)
template <int CTRL>
__device__ __forceinline__ float dpp_maxf(float m) {
  const float o = __uint_as_float((unsigned)dpp_i<CTRL>((int)__float_as_uint(m)));
  return fmaxf(m, o);
}
// u32 min step
template <int CTRL>
__device__ __forceinline__ unsigned dpp_minu(unsigned v) {
  const unsigned o = (unsigned)dpp_i<CTRL>((int)v);
  return o < v ? o : v;
}
// u64 (hi,lo) min step — knn extraction
template <int CTRL>
__device__ __forceinline__ void dpp_min64_step(unsigned& hi, unsigned& lo) {
  const unsigned ohi = (unsigned)dpp_i<CTRL>((int)hi);
  const unsigned olo = (unsigned)dpp_i<CTRL>((int)lo);
  const bool take = (ohi < hi) || (ohi == hi && olo < lo);
  hi = take ? ohi : hi;
  lo = take ? olo : lo;
}

// elementwise 3-way weighted sum, numpy op order, per component (bit-exact)
__device__ __forceinline__ float4 wsum3(float4 a, float4 b, float4 c,
                                        float w0, float w1, float w2) {
  float4 r;
  r.x = __fadd_rn(__fadd_rn(__fmul_rn(a.x, w0), __fmul_rn(b.x, w1)), __fmul_rn(c.x, w2));
  r.y = __fadd_rn(__fadd_rn(__fmul_rn(a.y, w0), __fmul_rn(b.y, w1)), __fmul_rn(c.y, w2));
  r.z = __fadd_rn(__fadd_rn(__fmul_rn(a.z, w0), __fmul_rn(b.z, w1)), __fmul_rn(c.z, w2));
  r.w = __fadd_rn(__fadd_rn(__fmul_rn(a.w, w0), __fmul_rn(b.w, w1)), __fmul_rn(c.w, w2));
  return r;
}

// ---------------- weight pack: W[o][c] -> WP[c/4][o][4] (pool pre-zeroed) ----
__global__ __launch_bounds__(256) void pack_w(
    const float* __restrict__ e1, const float* __restrict__ e2,
    const float* __restrict__ e3, const float* __restrict__ d1,
    const float* __restrict__ d2, const float* __restrict__ d3,
    const float* __restrict__ m1, float* __restrict__ dst) {
  int t = blockIdx.x * 256 + threadIdx.x;
  const float* src; int C, O; long dof;
  if (t < 4288) { src = e1; C = C1; O = O1; dof = WP_E1; }
  else if (t < 29248) { src = e2; C = C2; O = O2; dof = WP_E2; t -= 4288; }
  else if (t < 128320) { src = e3; C = C3; O = O3; dof = WP_E3; t -= 29248; }
  else if (t < 132608) { src = d1; C = C1; O = O1; dof = WP_D1; t -= 128320; }
  else if (t < 157568) { src = d2; C = C2; O = O2; dof = WP_D2; t -= 132608; }
  else if (t < 256640) { src = d3; C = C3; O = O3; dof = WP_D3; t -= 157568; }
  else if (t < 285312) { src = m1; C = 448; O = 64; dof = WP_M1; t -= 256640; }
  else return;
  const int o = t / C, c = t - o * C;
  dst[dof + ((long)(c >> 2) * O + o) * 4 + (c & 3)] = src[t];
}

// ---------------- furthest point sampling (fps8 + split reduce; r13 best) ----
// Measured A/B across 6 structures (us/dispatch, level-1): barrier 4-wave 505
// (THIS) < spin 659 ~ owner-publish 660 << dual-select 901 ~ single-wave 932.
// Winner = (max dist, min index): 6x v_max_f32 DPP (dist>=0 => float order ==
// bit order) -> wmax; then u32-min over j among dist-ties. Strict '>' over
// ascending k keeps first occurrence => jnp.argmax bit-exact.
template <int N, int NPOINT>
__global__ __launch_bounds__(256, 1) void fps8(const float* __restrict__ pts,
                                               long s1, long s2,
                                               float* __restrict__ out,
                                               long o1, long o2,
                                               const float* __restrict__ cfsrc,
                                               float* __restrict__ cfdst,
                                               int copy_y) {
  if ((int)blockIdx.y == copy_y) {  // merged copyframe
    const int b = blockIdx.x;
    for (int e = threadIdx.x; e < N0 * 3; e += 256)
      cfdst[(long)b * N0 * 3 + e] = cfsrc[((long)b * LF + (LF / 2 - 1)) * N0 * 3 + e];
    return;
  }
  constexpr int K = N / 256;
  const float* p = pts + (long)blockIdx.x * s1 + (long)blockIdx.y * s2;
  float* outb = out + (long)blockIdx.x * o1 + (long)blockIdx.y * o2;
  const int tid = threadIdx.x;
  const int lane = tid & 63;
  const int wid = tid >> 6;
  __shared__ float4 sp[N];
  __shared__ float sel[NPOINT * 3];
  __shared__ unsigned long long wbest[2][4];
  float ppx[K], ppy[K], ppz[K], dist[K];
#pragma unroll
  for (int k = 0; k < K; ++k) {
    const int j = k * 256 + tid;
    const float x = p[3 * j + 0], y = p[3 * j + 1], z = p[3 * j + 2];
    ppx[k] = x; ppy[k] = y; ppz[k] = z;
    sp[j] = make_float4(x, y, z, 0.f);
    dist[k] = 1e10f;
  }
  __syncthreads();
  const float4 c0 = sp[0];
  float lx = c0.x, ly = c0.y, lz = c0.z;
  for (int i = 0; i < NPOINT; ++i) {
    if (tid == 0) {
      sel[3 * i + 0] = lx; sel[3 * i + 1] = ly; sel[3 * i + 2] = lz;
    }
    float bdm = 0.f;
    int bk = 0;
#pragma unroll
    for (int k = 0; k < K; ++k) {
      const float d = sq3(ppx[k], ppy[k], ppz[k], lx, ly, lz);
      const float dm = fminf(dist[k], d);
      dist[k] = dm;
      const bool take = dm > bdm;  // strict > keeps smallest k (first occurrence)
      bdm = take ? dm : bdm;
      bk = take ? k : bk;
    }
    // wave max of dist (single-op DPP steps)
    float mx = bdm;
    mx = dpp_maxf<0x111>(mx);
    mx = dpp_maxf<0x112>(mx);
    mx = dpp_maxf<0x114>(mx);
    mx = dpp_maxf<0x118>(mx);
    mx = dpp_maxf<0x142>(mx);
    mx = dpp_maxf<0x143>(mx);
    const float wmax = __uint_as_float(
        (unsigned)__builtin_amdgcn_readlane((int)__float_as_uint(mx), 63));
    // min index among dist-ties
    unsigned cand = (bdm == wmax) ? (unsigned)((bk << 8) + tid) : 0xFFFFFFFFu;
    cand = dpp_minu<0x111>(cand);
    cand = dpp_minu<0x112>(cand);
    cand = dpp_minu<0x114>(cand);
    cand = dpp_minu<0x118>(cand);
    cand = dpp_minu<0x142>(cand);
    cand = dpp_minu<0x143>(cand);
    const unsigned minj = (unsigned)__builtin_amdgcn_readlane((int)cand, 63);
    if (lane == 63)
      wbest[i & 1][wid] =
          ((unsigned long long)__float_as_uint(wmax) << 32) | (2047u - minj);
    __syncthreads();
    unsigned long long gk = 0ull;
#pragma unroll
    for (int w = 0; w < 4; ++w) {
      const unsigned long long e = wbest[i & 1][w];
      gk = (e > gk) ? e : gk;
    }
    const int gidx = 2047 - (int)(gk & 0x7FFull);
    const float4 c = sp[gidx];
    lx = c.x; ly = c.y; lz = c.z;
  }
  __syncthreads();
  for (int e = tid; e < NPOINT * 3; e += 256) outb[e] = sel[e];
}

// ---------------- wave-parallel ball query (first ns in-range, ascending) ----
template <int NS>
__device__ __forceinline__ void wave_bq(float qx, float qy, float qz,
                                        const float* __restrict__ src, int Ns,
                                        float r2, int* __restrict__ sidx, int lane) {
  int cnt = 0;
  for (int base = 0; base < Ns && cnt < NS; base += 64) {
    const int j = base + lane;
    bool in = false;
    if (j < Ns)
      in = sq3(qx, qy, qz, src[3 * j], src[3 * j + 1], src[3 * j + 2]) < r2;
    const unsigned long long mask = __ballot(in);
    const int pos = cnt + (int)__popcll(mask & ((1ull << lane) - 1ull));
    if (in && pos < NS) sidx[pos] = j;
    cnt += (int)__popcll(mask);
  }
  const int cc = cnt < NS ? cnt : NS;
  const int fill = (cc > 0) ? sidx[0] : 0;
  if (lane >= cc && lane < NS) sidx[lane] = fill;
}

// ---------------- fused multi-cell (+knn) dispatch ----------------
struct FusedArgs {
  int n1, n2, n3, nk;
  const float *c1_xc, *c1_xp, *c1_W, *c1_Sp; float* c1_Sc;
  const float *c2_xc, *c2_xp, *c2_W, *c2_Sp, *c2_S1; float* c2_Sc;
  const float *c3_xc, *c3_xp, *c3_W, *c3_Sp, *c3_S2; float* c3_Sc;
  const float *k_xc, *k_frame;
  int *ii2, *ii1, *ii0;
  float *iw2, *iw1, *iw0;
  float r2c1, r2c2, r2q2, r2c3, r2q3;
};

__global__ __launch_bounds__(256) void fused_cells(FusedArgs a) {
  __shared__ __align__(16) float smem[3312];
  const int tid = threadIdx.x;
  const int lane = tid & 63;
  const int wave = tid >> 6;
  int bid = blockIdx.x;

  if (bid < a.n1) {  // -------- cell level-1 (4 wave-units/block) --------
    float* corr2 = smem + (size_t)wave * 828;  // [NS1][C41]=816 + 12 sidx
    int* sidx = (int*)(corr2 + 816);
    const int u = bid * 4 + wave;
    const int b = u >> 10, m = u & (M1 - 1);
    const float* p1 = a.c1_xc + (long)b * XS + 3 * m;
    const float p1x = p1[0], p1y = p1[1], p1z = p1[2];
    const float* p2b = a.c1_xp + (long)b * XS;
    wave_bq<NS1>(p1x, p1y, p1z, p2b, M1, a.r2c1, sidx, lane);
    __builtin_amdgcn_wave_barrier();
    for (int e = lane; e < NS1 * C41; e += 64) {
      const int s = e / C41, c = e - s * C41;
      const int j = sidx[s];
      float v;
      if (c < O1) {
        v = a.c1_Sp[((long)b * M1 + j) * O1 + c];
      } else if (c < C1) {
        const int d = c - O1;
        v = __fsub_rn(p2b[3 * j + d], (d == 0) ? p1x : ((d == 1) ? p1y : p1z));
      } else {
        v = 0.f;  // pad
      }
      corr2[e] = v;
    }
    __builtin_amdgcn_wave_barrier();
    const float4* wp4 = (const float4*)a.c1_W;
    float accs[NS1];
#pragma unroll
    for (int s = 0; s < NS1; ++s) accs[s] = 0.f;
    for (int q = 0; q < C41 / 4; ++q) {
      const float4 wv = wp4[(long)q * O1 + lane];
#pragma unroll
      for (int s = 0; s < NS1; ++s) {
        const float4 cv = *(const float4*)(corr2 + s * C41 + 4 * q);
        float acc = accs[s];
        acc = fmaf(wv.x, cv.x, acc);
        acc = fmaf(wv.y, cv.y, acc);
        acc = fmaf(wv.z, cv.z, acc);
        acc = fmaf(wv.w, cv.w, acc);
        accs[s] = acc;
      }
    }
    float best = accs[0];
#pragma unroll
    for (int s = 1; s < NS1; ++s) best = fmaxf(best, accs[s]);
    a.c1_Sc[((long)b * M1 + m) * O1 + lane] = best;
    return;
  }
  bid -= a.n1;

  if (bid < a.n2) {  // -------- cell level-2 (2 128-thr units/block) --------
    const int half = tid >> 7;
    const int ht = tid & 127;
    const int hw = (tid >> 6) & 1;
    float* base = smem + (size_t)half * 1644;
    float* corr2 = base;                 // [NS2][C42] = 1568
    int* sidx = (int*)(base + 1568);     // 8
    int* sfidx = (int*)(base + 1576);    // 4
    float* feat = base + 1580;           // 64
    const int u = bid * 2 + half;
    const int b = u >> 9, m = u & (M2 - 1);
    const float* p1 = a.c2_xc + (long)b * XS + 3 * m;
    const float p1x = p1[0], p1y = p1[1], p1z = p1[2];
    const float* p2b = a.c2_xp + (long)b * XS;
    if (hw == 0)
      wave_bq<NS2>(p1x, p1y, p1z, p2b, M2, a.r2c2, sidx, lane);
    else
      wave_bq<NSQ>(p1x, p1y, p1z, a.c2_xc + (long)b * XS, M1, a.r2q2, sfidx, lane);
    __syncthreads();
    if (ht < O1) {
      float bv = -3.0e38f;
#pragma unroll
      for (int s = 0; s < NSQ; ++s)
        bv = fmaxf(bv, a.c2_S1[((long)b * M1 + sfidx[s]) * O1 + ht]);
      feat[ht] = bv;
    }
    __syncthreads();
    for (int e = ht; e < NS2 * C42; e += 128) {
      const int s = e / C42, c = e - s * C42;
      const int j = sidx[s];
      float v;
      if (c < O2) {
        v = a.c2_Sp[((long)b * M2 + j) * O2 + c];
      } else if (c < O2 + O1) {
        v = feat[c - O2];
      } else if (c < C2) {
        const int d = c - O2 - O1;
        v = __fsub_rn(p2b[3 * j + d], (d == 0) ? p1x : ((d == 1) ? p1y : p1z));
      } else {
        v = 0.f;
      }
      corr2[e] = v;
    }
    __syncthreads();
    const float4* wp4 = (const float4*)a.c2_W;
    float accs[NS2];
#pragma unroll
    for (int s = 0; s < NS2; ++s) accs[s] = 0.f;
    for (int q = 0; q < C42 / 4; ++q) {
      const float4 wv = wp4[(long)q * O2 + ht];
#pragma unroll
      for (int s = 0; s < NS2; ++s) {
        const float4 cv = *(const float4*)(corr2 + s * C42 + 4 * q);
        float acc = accs[s];
        acc = fmaf(wv.x, cv.x, acc);
        acc = fmaf(wv.y, cv.y, acc);
        acc = fmaf(wv.z, cv.z, acc);
        acc = fmaf(wv.w, cv.w, acc);
        accs[s] = acc;
      }
    }
    float best = accs[0];
#pragma unroll
    for (int s = 1; s < NS2; ++s) best = fmaxf(best, accs[s]);
    a.c2_Sc[((long)b * M2 + m) * O2 + ht] = best;
    return;
  }
  bid -= a.n2;

  if (bid < a.n3) {  // -------- cell level-3 (1 unit/block, 256 thr) --------
    float* corr2 = smem;                 // [NS3][C43] = 1552
    int* sidx = (int*)(smem + 1552);
    int* sfidx = (int*)(smem + 1556);
    float* feat = smem + 1560;           // 128
    const int b = bid >> 8, m = bid & (M3 - 1);
    const float* p1 = a.c3_xc + (long)b * XS + 3 * m;
    const float p1x = p1[0], p1y = p1[1], p1z = p1[2];
    const float* p2b = a.c3_xp + (long)b * XS;
    if (wave == 0)
      wave_bq<NS3>(p1x, p1y, p1z, p2b, M3, a.r2c3, sidx, lane);
    else if (wave == 1)
      wave_bq<NSQ>(p1x, p1y, p1z, a.c3_xc + (long)b * XS, M2, a.r2q3, sfidx, lane);
    __syncthreads();
    if (tid < O2) {
      float bv = -3.0e38f;
#pragma unroll
      for (int s = 0; s < NSQ; ++s)
        bv = fmaxf(bv, a.c3_S2[((long)b * M2 + sfidx[s]) * O2 + tid]);
      feat[tid] = bv;
    }
    __syncthreads();
    for (int e = tid; e < NS3 * C43; e += 256) {
      const int s = e / C43, c = e - s * C43;
      const int j = sidx[s];
      float v;
      if (c < O3) {
        v = a.c3_Sp[((long)b * M3 + j) * O3 + c];
      } else if (c < O3 + O2) {
        v = feat[c - O3];
      } else if (c < C3) {
        const int d = c - O3 - O2;
        v = __fsub_rn(p2b[3 * j + d], (d == 0) ? p1x : ((d == 1) ? p1y : p1z));
      } else {
        v = 0.f;
      }
      corr2[e] = v;
    }
    __syncthreads();
    const float4* wp4 = (const float4*)a.c3_W;
    float accs[NS3];
#pragma unroll
    for (int s = 0; s < NS3; ++s) accs[s] = 0.f;
    for (int q = 0; q < C43 / 4; ++q) {
      const float4 wv = wp4[(long)q * O3 + tid];
#pragma unroll
      for (int s = 0; s < NS3; ++s) {
        const float4 cv = *(const float4*)(corr2 + s * C43 + 4 * q);
        float acc = accs[s];
        acc = fmaf(wv.x, cv.x, acc);
        acc = fmaf(wv.y, cv.y, acc);
        acc = fmaf(wv.z, cv.z, acc);
        acc = fmaf(wv.w, cv.w, acc);
        accs[s] = acc;
      }
    }
    float best = accs[0];
#pragma unroll
    for (int s = 1; s < NS3; ++s) best = fmaxf(best, accs[s]);
    a.c3_Sc[((long)b * M3 + m) * O3 + tid] = best;
    return;
  }
  bid -= a.n3;

  {  // -------- knn: wave-per-query 3-NN (3584 blocks: 512 + 1024 + 2048) -----
    int q, Mu, Mk;
    const float* unk; long ustr; int* oi; float* ow;
    if (bid < 512) {
      q = bid * 4 + wave; Mu = M2; Mk = M3; unk = a.k_xc; ustr = XS;
      oi = a.ii2; ow = a.iw2;
    } else if (bid < 1536) {
      q = (bid - 512) * 4 + wave; Mu = M1; Mk = M2; unk = a.k_xc; ustr = XS;
      oi = a.ii1; ow = a.iw1;
    } else {
      q = (bid - 1536) * 4 + wave; Mu = N0; Mk = M1; unk = a.k_frame; ustr = 3L * N0;
      oi = a.ii0; ow = a.iw0;
    }
    const int b = q / Mu, m = q - b * Mu;
    const float* qq = unk + (long)b * ustr + (long)m * 3;
    const float qx = qq[0], qy = qq[1], qz = qq[2];
    const float* s = a.k_xc + (long)b * XS;
    unsigned long long k0 = ~0ull, k1 = ~0ull, k2 = ~0ull;
    const int steps = Mk >> 6;
    for (int t7 = 0; t7 < steps; ++t7) {
      const int j = (t7 << 6) + lane;
      const float dd = sq3(qx, qy, qz, s[3 * j], s[3 * j + 1], s[3 * j + 2]);
      const unsigned long long key =
          ((unsigned long long)__float_as_uint(dd) << 32) | (unsigned)j;
      if (key < k0) { k2 = k1; k1 = k0; k0 = key; }
      else if (key < k1) { k2 = k1; k1 = key; }
      else if (key < k2) { k2 = key; }
    }
    float dw[3]; int jw[3];
#pragma unroll
    for (int r = 0; r < 3; ++r) {
      unsigned mhi = (unsigned)(k0 >> 32), mlo = (unsigned)k0;
      dpp_min64_step<0x111>(mhi, mlo);
      dpp_min64_step<0x112>(mhi, mlo);
      dpp_min64_step<0x114>(mhi, mlo);
      dpp_min64_step<0x118>(mhi, mlo);
      dpp_min64_step<0x142>(mhi, mlo);
      dpp_min64_step<0x143>(mhi, mlo);
      const unsigned whi = (unsigned)__builtin_amdgcn_readlane((int)mhi, 63);
      const unsigned wlo = (unsigned)__builtin_amdgcn_readlane((int)mlo, 63);
      const unsigned long long w = ((unsigned long long)whi << 32) | wlo;
      dw[r] = __uint_as_float(whi);
      jw[r] = (int)wlo;
      if (k0 == w) { k0 = k1; k1 = k2; k2 = ~0ull; }
    }
    const float r0 = 1.0f / __fadd_rn(dw[0], 1e-8f);
    const float r1 = 1.0f / __fadd_rn(dw[1], 1e-8f);
    const float r2 = 1.0f / __fadd_rn(dw[2], 1e-8f);
    const float sum = __fadd_rn(__fadd_rn(r0, r1), r2);
    if (lane == 0) {
      ow[q * 3 + 0] = r0 / sum;
      ow[q * 3 + 1] = r1 / sum;
      ow[q * 3 + 2] = r2 / sum;
      oi[q * 3 + 0] = jw[0];
      oi[q * 3 + 1] = jw[1];
      oi[q * 3 + 2] = jw[2];
    }
  }
}

// ---------------- buildl2 (float4 per thread, fully coalesced) ----------------
__global__ __launch_bounds__(256) void buildl2_kernel(const float* __restrict__ S3c,
                                                      const float* __restrict__ S2c,
                                                      const float* __restrict__ S1c,
                                                      const int* __restrict__ ii1,
                                                      const float* __restrict__ iw1,
                                                      const int* __restrict__ ii2,
                                                      const float* __restrict__ iw2,
                                                      float* __restrict__ l2) {
  const int t = blockIdx.x * 256 + threadIdx.x;  // exact: B*M1*112
  const int bm = t / 112;
  const int c0 = (t - bm * 112) * 4;
  const int b = bm >> 10;
  const int* id1 = ii1 + (long)bm * 3;
  const float* w1 = iw1 + (long)bm * 3;
  float4 v;
  if (c0 < O3) {
    float4 v2[3];
#pragma unroll
    for (int k = 0; k < 3; ++k) {
      const int m2 = id1[k];
      const int* id2 = ii2 + ((long)b * M2 + m2) * 3;
      const float* w2 = iw2 + ((long)b * M2 + m2) * 3;
      const float4 s0 = *(const float4*)(S3c + ((long)b * M3 + id2[0]) * O3 + c0);
      const float4 s1 = *(const float4*)(S3c + ((long)b * M3 + id2[1]) * O3 + c0);
      const float4 s2 = *(const float4*)(S3c + ((long)b * M3 + id2[2]) * O3 + c0);
      v2[k] = wsum3(s0, s1, s2, w2[0], w2[1], w2[2]);
    }
    v = wsum3(v2[0], v2[1], v2[2], w1[0], w1[1], w1[2]);
  } else if (c0 < 384) {
    const int cc = c0 - O3;
    const float4 s0 = *(const float4*)(S2c + ((long)b * M2 + id1[0]) * O2 + cc);
    const float4 s1 = *(const float4*)(S2c + ((long)b * M2 + id1[1]) * O2 + cc);
    const float4 s2 = *(const float4*)(S2c + ((long)b * M2 + id1[2]) * O2 + cc);
    v = wsum3(s0, s1, s2, w1[0], w1[1], w1[2]);
  } else {
    v = *(const float4*)(S1c + (long)bm * O1 + (c0 - 384));
  }
  *(float4*)(l2 + (long)bm * 448 + c0) = v;
}

// ---------------- mlp: interp-to-l1 + 2-layer MLP + frame update -------------
__global__ __launch_bounds__(256) void mlp_kernel(const float* __restrict__ l2,
                                                  const int* __restrict__ ii,
                                                  const float* __restrict__ iw,
                                                  const float* __restrict__ W1P,
                                                  const float* __restrict__ b1,
                                                  const float* __restrict__ W2,
                                                  const float* __restrict__ b2,
                                                  float* __restrict__ frame,
                                                  float* __restrict__ out, int td) {
  __shared__ __align__(16) float smem[4 * 512];
  const int lane = threadIdx.x & 63;
  const int wave = threadIdx.x >> 6;
  float* col = smem + (size_t)wave * 512;
  float* h = col + 448;
  const int u = blockIdx.x * 4 + wave;  // exact: B*N0 units
  const int b = u >> 11, n = u & (N0 - 1);
  const int* id = ii + (long)u * 3;
  const float* w = iw + (long)u * 3;
  const float w0 = w[0], w1 = w[1], w2v = w[2];
  const float4* r0 = (const float4*)(l2 + ((long)b * M1 + id[0]) * 448);
  const float4* r1 = (const float4*)(l2 + ((long)b * M1 + id[1]) * 448);
  const float4* r2 = (const float4*)(l2 + ((long)b * M1 + id[2]) * 448);
  float4* col4 = (float4*)col;
  for (int q = lane; q < 112; q += 64)
    col4[q] = wsum3(r0[q], r1[q], r2[q], w0, w1, w2v);
  __builtin_amdgcn_wave_barrier();
  const float4* wp4 = (const float4*)W1P;
  float acc = b1[lane];
  for (int q = 0; q < 112; ++q) {
    const float4 wv = wp4[(long)q * 64 + lane];
    const float4 cv = col4[q];
    acc = fmaf(wv.x, cv.x, acc);
    acc = fmaf(wv.y, cv.y, acc);
    acc = fmaf(wv.z, cv.z, acc);
    acc = fmaf(wv.w, cv.w, acc);
  }
  h[lane] = fmaxf(acc, 0.0f);
  __builtin_amdgcn_wave_barrier();
  if (lane < 3) {
    const float* w2r = W2 + lane * 64;
    float acc2 = b2[lane];
    for (int c = 0; c < 64; ++c) acc2 = fmaf(w2r[c], h[c], acc2);
    const float nf = frame[(long)u * 3 + lane] + acc2;
    frame[(long)u * 3 + lane] = nf;
    out[(((long)b * 4 + td) * N0 + n) * 3 + lane] = nf;
  }
}

extern "C" void kernel_launch(void* const* d_in, const int* in_sizes, int n_in,
                              void* d_out, int out_size, void* d_ws, size_t ws_size,
                              hipStream_t stream) {
  const float* xyzs = (const float*)d_in[0];
  const float* enw[3] = {(const float*)d_in[1], (const float*)d_in[2], (const float*)d_in[3]};
  const float* dew[3] = {(const float*)d_in[4], (const float*)d_in[5], (const float*)d_in[6]};
  const float* mw1 = (const float*)d_in[7];
  const float* mb1 = (const float*)d_in[8];
  const float* mw2 = (const float*)d_in[9];
  const float* mb2 = (const float*)d_in[10];
  float* out = (float*)d_out;

  float* ws = (float*)d_ws;
  size_t off = 0;
  auto alloc = [&](size_t nn) { float* p = ws + off; off += nn; return p; };
  const long st1 = (long)B * M1 * 3;
  float* frame = alloc((size_t)B * N0 * 3);
  float* xyz1e = alloc((size_t)4 * st1);
  float* xyz1d[2] = {alloc((size_t)st1), alloc((size_t)st1)};
  float* z1 = alloc((size_t)st1);
  float* S1bf[2] = {alloc((size_t)B * O1 * M1), alloc((size_t)B * O1 * M1)};
  float* S2bf[2] = {alloc((size_t)B * O2 * M2), alloc((size_t)B * O2 * M2)};
  float* S3bf[2] = {alloc((size_t)B * O3 * M3), alloc((size_t)B * O3 * M3)};
  float* l2 = alloc((size_t)B * 448 * M1);
  float* iw0 = alloc((size_t)B * N0 * 3);
  int* ii0 = (int*)alloc((size_t)B * N0 * 3);
  float* iw1 = alloc((size_t)B * M1 * 3);
  int* ii1 = (int*)alloc((size_t)B * M1 * 3);
  float* iw2 = alloc((size_t)B * M2 * 3);
  int* ii2 = (int*)alloc((size_t)B * M2 * 3);
  float* wt = alloc((size_t)WP_TOT);

  hipMemsetAsync(z1, 0, (size_t)st1 * 4, stream);
  hipMemsetAsync(S1bf[1], 0, (size_t)B * O1 * M1 * 4, stream);
  hipMemsetAsync(S2bf[1], 0, (size_t)B * O2 * M2 * 4, stream);
  hipMemsetAsync(S3bf[1], 0, (size_t)B * O3 * M3 * 4, stream);
  hipMemsetAsync(wt, 0, (size_t)WP_TOT * 4, stream);  // pad weights must be 0

  double r;
  r = 4.0 + 1e-6;             const float r2c1 = (float)(r * r);
  r = 2.0 * 4.0 / 4.0 + 1e-6; const float r2q2 = (float)(r * r);
  r = 2.0 * 4.0 + 1e-6;       const float r2c2 = (float)(r * r);
  r = 4.0 * 4.0 / 4.0 + 1e-6; const float r2q3 = (float)(r * r);
  r = 3.0 * 4.0 + 1e-6;       const float r2c3 = (float)(r * r);

  pack_w<<<dim3((285312 + 255) / 256), 256, 0, stream>>>(
      enw[0], enw[1], enw[2], dew[0], dew[1], dew[2], mw1, wt);

  // encoder FPS (4 timesteps) + merged copyframe (y==4)
  fps8<2048, 1024><<<dim3(B, 5), 256, 0, stream>>>(xyzs, (long)LF * N0 * 3,
                                                   (long)N0 * 3, xyz1e, XS, st1,
                                                   xyzs, frame, 4);

  // t=4: frame == xyzs[:,3] bit-exactly => reuse encoder t=3's FPS result.
  const float* x1_of_t[LF] = {
      xyz1e + 0 * st1, xyz1e + 1 * st1, xyz1e + 2 * st1, xyz1e + 3 * st1,
      xyz1e + 3 * st1, xyz1d[0], xyz1d[1], xyz1d[0]};

  const float* wp1[2] = {wt + WP_E1, wt + WP_D1};
  const float* wp2[2] = {wt + WP_E2, wt + WP_D2};
  const float* wp3[2] = {wt + WP_E3, wt + WP_D3};

  auto launch_fused = [&](int t1, int t2, int t3, int tk) {
    FusedArgs a{};
    int nb = 0;
    if (t1 >= 0) {
      a.n1 = B * M1 / 4;
      a.c1_xc = x1_of_t[t1];
      a.c1_xp = (t1 == 0) ? z1 : x1_of_t[t1 - 1];
      a.c1_W = wp1[t1 >= 4];
      a.c1_Sp = S1bf[1 - (t1 & 1)];
      a.c1_Sc = S1bf[t1 & 1];
      nb += a.n1;
    }
    if (t2 >= 0) {
      a.n2 = B * M2 / 2;
      a.c2_xc = x1_of_t[t2];
      a.c2_xp = (t2 == 0) ? z1 : x1_of_t[t2 - 1];
      a.c2_W = wp2[t2 >= 4];
      a.c2_Sp = S2bf[1 - (t2 & 1)];
      a.c2_S1 = S1bf[t2 & 1];
      a.c2_Sc = S2bf[t2 & 1];
      nb += a.n2;
    }
    if (t3 >= 0) {
      a.n3 = B * M3;
      a.c3_xc = x1_of_t[t3];
      a.c3_xp = (t3 == 0) ? z1 : x1_of_t[t3 - 1];
      a.c3_W = wp3[t3 >= 4];
      a.c3_Sp = S3bf[1 - (t3 & 1)];
      a.c3_S2 = S2bf[t3 & 1];
      a.c3_Sc = S3bf[t3 & 1];
      nb += a.n3;
    }
    if (tk >= 0) {
      a.nk = 3584;  // wave-per-query knn: 512 (ii2) + 1024 (ii1) + 2048 (ii0)
      a.k_xc = x1_of_t[tk];
      a.k_frame = frame;
      a.ii2 = ii2; a.ii1 = ii1; a.ii0 = ii0;
      a.iw2 = iw2; a.iw1 = iw1; a.iw0 = iw0;
      nb += a.nk;
    }
    a.r2c1 = r2c1; a.r2c2 = r2c2; a.r2q2 = r2q2; a.r2c3 = r2c3; a.r2q3 = r2q3;
    fused_cells<<<dim3((unsigned)nb), 256, 0, stream>>>(a);
  };

  auto tail = [&](int t) {
    buildl2_kernel<<<dim3(B * M1 * 112 / 256), 256, 0, stream>>>(
        S3bf[t & 1], S2bf[t & 1], S1bf[t & 1], ii1, iw1, ii2, iw2, l2);
    mlp_kernel<<<dim3(B * N0 / 4), 256, 0, stream>>>(
        l2, ii0, iw0, wt + WP_M1, mb1, mw2, mb2, frame, out, t - 4);
  };

  // encoder software pipeline + t=4 head (diagonal: independent tasks merged)
  launch_fused(0, -1, -1, -1);
  launch_fused(1, 0, -1, -1);
  launch_fused(2, 1, 0, -1);
  launch_fused(3, 2, 1, -1);
  launch_fused(4, 3, 2, 4);
  launch_fused(-1, 4, 3, -1);
  launch_fused(-1, -1, 4, -1);
  tail(4);

  for (int t = 5; t < LF; ++t) {
    fps8<2048, 1024><<<dim3(B, 1), 256, 0, stream>>>(frame, (long)N0 * 3, 0,
                                                     (float*)x1_of_t[t], XS, 0,
                                                     nullptr, nullptr, -1);
    launch_fused(t, -1, -1, t);
    launch_fused(-1, t, -1, -1);
    launch_fused(-1, -1, t, -1);
    tail(t);
  }
  (void)in_sizes; (void)n_in; (void)out_size; (void)ws_size;
}